// Round 4
// baseline (252.446 us; speedup 1.0000x reference)
//
#include <hip/hip_runtime.h>

// filtfilt (order-2 biquad, odd-ext pad=9) over 1024 rows x 32768 fp32.
//
// R7: pure-register, fully lane-independent rewrite. R6's profile (VALU 25%,
// HBM 29%, conflicts 0, nothing saturated) showed the cost was the per-wave
// serial phase chain (stage->fence->fwd->seam->fence->bwd->fence->out, 4+
// dependent memory round-trips). With C=32 the row tiles EXACTLY
// (16 segs x 64 lanes x 32 = 32768): each lane loads its own 64-float window
// (WF=16 warmup | 32 outputs | WB=16 bwd-warmup) straight to registers,
// runs fwd over all 64 (producing its OWN bwd-warmup y1 -- no cross-lane
// seam), bwd over 48, stores 8 float4. No LDS, no fences, no shuffles, no
// masked stores; ONE vmcnt wait per wave. Lane stride = 128 B = 1 cacheline
// -> every load instr is 64 consecutive lines (streaming-perfect for HBM;
// the 2x window overlap is served by L1/L2).
// Warmup 16 steps (err 0.577^16 ~ 1.5e-4); edges exact: seg0/lane0 fwd
// starts on 7 zeros + odd-ext (z=0 preserved to t=0), seg15/lane63 bwd
// starts on y1=0 beyond LTOT (z=0 preserved to t=LTOT-1), as in R3/R6.

#define N_COLS 32768
#define PAD 9
#define LTOT  (N_COLS + 2 * PAD)   // 32786
#define WF 16
#define WB 16
#define C  32                      // outputs per lane
#define LANES 64
#define P   (C * LANES)            // 2048 outputs per wave
#define NSEG (N_COLS / P)          // 16 -- exact tiling, power of 2
#define WIN (WF + C + WB)          // 64 floats per lane
#define NLD (WIN / 4)              // 16 float4 loads per lane
#define WPB 4
#define TPB 256

__launch_bounds__(TPB, 4)
__global__ void filtfilt_kernel(const float* __restrict__ x,
                                const float* __restrict__ bco,
                                const float* __restrict__ aco,
                                float* __restrict__ out,
                                int rows) {
    const int tid = threadIdx.x;
    const int wid = tid >> 6;
    const int lane = tid & 63;
    const int W = blockIdx.x * WPB + wid;  // global wave index
    const int row = W >> 4;                // NSEG == 16
    const int seg = W & (NSEG - 1);
    if (row >= rows) return;

    const float inv_a0 = 1.0f / aco[0];
    const float B0 = bco[0] * inv_a0;
    const float B1 = bco[1] * inv_a0;
    const float B2 = bco[2] * inv_a0;
    const float A1 = aco[1] * inv_a0;
    const float A2 = aco[2] * inv_a0;

    const float* __restrict__ xrow = x + (size_t)row * N_COLS;
    // x-index of window start; xe coord of element k is  t = xbase + PAD + k
    const int xbase = seg * P + C * lane - WF;   // -16 .. 32720, %4 == 0

    // ---- 16 independent float4 loads, clamped into [0, N-4]; one wait.
    // Clamped (garbage-but-finite) elements are exactly the ones patched.
    float v[WIN];
#pragma unroll
    for (int j = 0; j < NLD; ++j) {
        int idx = xbase + 4 * j;
        idx = (idx < 0) ? 0 : idx;
        idx = (idx > N_COLS - 4) ? (N_COLS - 4) : idx;
        *(float4*)(v + 4 * j) = *(const float4*)(xrow + idx);
    }

    // ---- left edge: only seg 0 / lane 0 (xbase = -16, so t = k - 7).
    // t < 0 -> 0 (keeps z=0 through t=0 => fwd EXACT); 0<=t<9 -> odd-ext.
    if (seg == 0 && lane == 0) {
        const float x0 = xrow[0];
#pragma unroll
        for (int k = 0; k < WF; ++k) {
            const int t = k - (WF - PAD);          // -7 .. 8
            v[k] = (t < 0) ? 0.0f : (2.0f * x0 - xrow[PAD - t]);
        }
    }
    // ---- right edge: only seg 15 / lane 63 (xbase = 32720, t = 32729 + k).
    // t in [32777, 32786) -> odd-ext: 2*x[N-1] - x[65543 - t] = x[32814 - k];
    // t >= 32786 -> 0.
    if (seg == NSEG - 1 && lane == LANES - 1) {
        const float xl = xrow[N_COLS - 1];
#pragma unroll
        for (int k = 48; k < 57; ++k)
            v[k] = 2.0f * xl - xrow[32814 - k];
#pragma unroll
        for (int k = 57; k < WIN; ++k) v[k] = 0.0f;
    }

    // ---- forward biquad over all 64 elements (z=0 at window start).
    // y1 kept only for k >= WF (outputs + own bwd warmup).
    {
        float z0 = 0.0f, z1 = 0.0f;
#pragma unroll
        for (int k = 0; k < WIN; ++k) {
            const float xv = v[k];
            const float y = fmaf(B0, xv, z0);
            z0 = fmaf(-A1, y, fmaf(B1, xv, z1));
            z1 = fmaf(B2, xv, -A2 * y);
            if (k >= WF) v[k] = y;
        }
    }

    // ---- right edge: y1 at t >= LTOT must read as zero so the bwd pass
    // carries z=0 exactly to t = LTOT-1 (reference bwd start).
    if (seg == NSEG - 1 && lane == LANES - 1) {
#pragma unroll
        for (int k = 57; k < WIN; ++k) v[k] = 0.0f;
    }

    // ---- backward biquad: warmup over k = 63..48 (own y1), outputs 47..16.
    {
        float z0 = 0.0f, z1 = 0.0f;
#pragma unroll
        for (int k = WIN - 1; k >= WF; --k) {
            const float xv = v[k];
            const float y = fmaf(B0, xv, z0);
            z0 = fmaf(-A1, y, fmaf(B1, xv, z1));
            z1 = fmaf(B2, xv, -A2 * y);
            if (k < WF + C) v[k] = y;
        }
    }

    // ---- 8 float4 stores (exact tiling -> no masking anywhere).
    float* __restrict__ orow = out + (size_t)row * N_COLS + (xbase + WF);
#pragma unroll
    for (int j = 0; j < C / 4; ++j)
        *(float4*)(orow + 4 * j) = *(const float4*)(v + WF + 4 * j);
}

extern "C" void kernel_launch(void* const* d_in, const int* in_sizes, int n_in,
                              void* d_out, int out_size, void* d_ws, size_t ws_size,
                              hipStream_t stream) {
    const float* x = (const float*)d_in[0];
    const float* b = (const float*)d_in[1];
    const float* a = (const float*)d_in[2];
    float* out = (float*)d_out;
    const int rows = out_size / N_COLS;                // 1024
    const int total_waves = rows * NSEG;               // 16384
    const int blocks = (total_waves + WPB - 1) / WPB;  // 4096
    filtfilt_kernel<<<blocks, TPB, 0, stream>>>(x, b, a, out, rows);
}

// Round 5
// 231.763 us; speedup vs baseline: 1.0892x; 1.0892x over previous
//
#include <hip/hip_runtime.h>

// filtfilt (order-2 biquad, odd-ext pad=9) over 1024 rows x 32768 fp32.
//
// R8 = R7's lane-independent compute + R3's dense global access, via swizzled
// all-b128 LDS staging.
//  - R7 insight kept: equal fwd/bwd chunks -> each lane produces its OWN
//    bwd-warmup y1 in registers. No cross-lane y1 seam, no y1 LDS round-trip.
//  - R7 flaw fixed: its 128B-lane-strided global loads/stores cost 64
//    cacheline-transactions per instr (~1536 line-cyc/wave through shared TA,
//    VALUBusy 16%, 98.7us). Here ALL global access is dense (staged via LDS).
//  - C=16 -> slice 1056 fl = 4224 B/wave -> 8 blocks/CU = 32 waves/CU (full).
//  - LDS XOR swizzle s^=((s>>4)&7)<<2: stride-16-float b128 window reads are
//    otherwise ~32-way bank conflicts (even lanes all hit banks 0-3). Swizzle
//    makes every access phase (dense stage-write, window-read, y2-write,
//    dense copy-out) exactly uniform: 8 lanes per 4-bank group = b128 floor.
//  - Stage loop fixed-trip (5x, clamped) + unrolled: 5 independent loads ->
//    ONE vmcnt wait (variable-trip loop serialized 4-5 HBM round-trips).
// Barrier-free: intra-wave LDS program order; compile-time fences at the 4
// cross-lane seams (stage->patch->windowread->y2write->copyout), zero runtime
// cost. Warmup 16/16 (err 0.577^16 ~ 1.5e-4); edges exact (seg0/lane0 fwd
// z=0 carried to t=0; seg31/lane63 bwd z=0 carried to t=LTOT-1).

#define N_COLS 32768
#define PAD 9
#define LTOT  (N_COLS + 2 * PAD)   // 32786
#define WF 16
#define WB 16
#define C  16                      // outputs per lane
#define LANES 64
#define P   (C * LANES)            // 1024 outputs per wave
#define NSEG (N_COLS / P)          // 32 -- exact tiling
#define WIN (WF + C + WB)          // 48 floats per lane
#define SLICE (WF + P + WB)        // 1056 floats = 33*32 (128B-multiple)
#define NV4 (SLICE / 4)            // 264 float4 per slice
#define WPB 4
#define TPB 256

// XOR bits[4:2] of the float index with bits[6:4] -> bank-uniform b128 at
// both stride-4 (dense) and stride-16 (window) access. Permutes within each
// 32-float (128 B) block; slice base is 128B-aligned so banks = bits[4:0].
#define SWZ(s) ((s) ^ ((((s) >> 4) & 7) << 2))

// Compile-time ordering fence between LDS phases (no runtime instructions).
#define LDS_PHASE_FENCE() do { asm volatile("" ::: "memory"); \
                               __builtin_amdgcn_sched_barrier(0); } while (0)

__launch_bounds__(TPB, 8)
__global__ void filtfilt_kernel(const float* __restrict__ x,
                                const float* __restrict__ bco,
                                const float* __restrict__ aco,
                                float* __restrict__ out,
                                int rows) {
    __shared__ __align__(128) float xs_all[WPB][SLICE];   // 16,896 B
    const int tid = threadIdx.x;
    const int wid = tid >> 6;
    const int lane = tid & 63;
    float* __restrict__ xs = xs_all[wid];

    const int W = blockIdx.x * WPB + wid;  // global wave index
    const int row = W >> 5;                // NSEG == 32
    const int seg = W & (NSEG - 1);
    if (row >= rows) return;               // wave-uniform

    const float inv_a0 = 1.0f / aco[0];
    const float B0 = bco[0] * inv_a0;
    const float B1 = bco[1] * inv_a0;
    const float B2 = bco[2] * inv_a0;
    const float A1 = aco[1] * inv_a0;
    const float A2 = aco[2] * inv_a0;

    const float* __restrict__ xrow = x + (size_t)row * N_COLS;
    // slice-local s holds xe[A + s], A = PAD + seg*P - WF; x-index = xoff + s
    const int xoff = seg * P - WF;

    // ---- stage: 5 fixed iterations (4.125 needed), clamped index -> all 5
    // loads issue independently, one vmcnt wait, then 5 swizzled b128 writes.
#pragma unroll
    for (int m = 0; m < 5; ++m) {
        int i = lane + LANES * m;
        i = (i > NV4 - 1) ? (NV4 - 1) : i;     // duplicate tail write (same value)
        int g = xoff + 4 * i;
        g = (g < 0) ? 0 : g;
        g = (g > N_COLS - 4) ? (N_COLS - 4) : g;
        *(float4*)(xs + SWZ(4 * i)) = *(const float4*)(xrow + g);
    }
    LDS_PHASE_FENCE();   // stage writes -> patch writes (WAW, cross-lane)

    // ---- left patch (seg0): s in [0,16), t = s-7: zeros then odd-ext.
    // Zeros keep fwd z=0 exactly through t=0 (reference fwd start).
    if (seg == 0 && lane < WF) {
        const int t = lane - (WF - PAD);       // -7..8
        xs[SWZ(lane)] = (t < 0) ? 0.0f : (2.0f * xrow[0] - xrow[PAD - t]);
    }
    // ---- right patch (seg31): s in [1040,1056), t = 32777+lane:
    // odd-ext for t<LTOT, zeros past -> bwd carries z=0 exactly to t=LTOT-1.
    if (seg == NSEG - 1 && lane < WF) {
        const int s = SLICE - WF + lane;
        xs[SWZ(s)] = (lane < PAD)
                   ? (2.0f * xrow[N_COLS - 1] - xrow[N_COLS - 2 - lane])
                   : 0.0f;
    }
    LDS_PHASE_FENCE();   // patch/stage writes -> window reads (cross-lane RAW)

    // ---- window read: 12 swizzled b128 (conflict-free), then fwd in regs.
    const int s0 = C * lane;
    float v[WIN];
#pragma unroll
    for (int j = 0; j < WIN / 4; ++j)
        *(float4*)(v + 4 * j) = *(const float4*)(xs + SWZ(s0 + 4 * j));
    {
        float z0 = 0.0f, z1 = 0.0f;
#pragma unroll
        for (int k = 0; k < WIN; ++k) {
            const float xv = v[k];
            const float y = fmaf(B0, xv, z0);
            z0 = fmaf(-A1, y, fmaf(B1, xv, z1));
            z1 = fmaf(B2, xv, -A2 * y);
            if (k >= WF) v[k] = y;             // outputs + own bwd warmup
        }
    }
    // ---- right edge: y1 at t >= LTOT must be zero for exact bwd start.
    // lane63/seg31: t = 32745 + k -> k >= 41.
    if (seg == NSEG - 1 && lane == LANES - 1) {
#pragma unroll
        for (int k = 41; k < WIN; ++k) v[k] = 0.0f;
    }
    // ---- backward: warmup on own y1 (k=47..32), outputs k=31..16.
    {
        float z0 = 0.0f, z1 = 0.0f;
#pragma unroll
        for (int k = WIN - 1; k >= WF; --k) {
            const float xv = v[k];
            const float y = fmaf(B0, xv, z0);
            z0 = fmaf(-A1, y, fmaf(B1, xv, z1));
            z1 = fmaf(B2, xv, -A2 * y);
            if (k < WF + C) v[k] = y;
        }
    }
    LDS_PHASE_FENCE();   // window reads -> y2 writes (cross-lane WAR: lane
                         // l+1's warmup reads overlap lane l's y2 region)

    // ---- y2 write in place: 4 swizzled b128 at s0+16..s0+32.
#pragma unroll
    for (int j = 0; j < C / 4; ++j)
        *(float4*)(xs + SWZ(s0 + WF + 4 * j)) = *(const float4*)(v + WF + 4 * j);
    LDS_PHASE_FENCE();   // y2 writes -> copy-out reads (cross-lane RAW)

    // ---- dense copy-out: 4 swizzled b128 reads -> 4 dense global stores.
    float* __restrict__ orow = out + (size_t)row * N_COLS + seg * P;
#pragma unroll
    for (int m = 0; m < P / 4 / LANES; ++m) {  // exactly 4
        const int i = lane + LANES * m;
        *(float4*)(orow + 4 * i) = *(const float4*)(xs + SWZ(WF + 4 * i));
    }
}

extern "C" void kernel_launch(void* const* d_in, const int* in_sizes, int n_in,
                              void* d_out, int out_size, void* d_ws, size_t ws_size,
                              hipStream_t stream) {
    const float* x = (const float*)d_in[0];
    const float* b = (const float*)d_in[1];
    const float* a = (const float*)d_in[2];
    float* out = (float*)d_out;
    const int rows = out_size / N_COLS;                // 1024
    const int total_waves = rows * NSEG;               // 32768
    const int blocks = total_waves / WPB;              // 8192
    filtfilt_kernel<<<blocks, TPB, 0, stream>>>(x, b, a, out, rows);
}